// Round 5
// baseline (237.726 us; speedup 1.0000x reference)
//
#include <hip/hip_runtime.h>

typedef _Float16 half8 __attribute__((ext_vector_type(8)));
typedef _Float16 half4 __attribute__((ext_vector_type(4)));
typedef float floatx16 __attribute__((ext_vector_type(16)));

#define MFMA_F16(A, B, C) __builtin_amdgcn_mfma_f32_32x32x16_f16(A, B, C, 0, 0, 0)

constexpr int Bn = 4;     // batch
constexpr int Cc = 256;   // channels
constexpr int Cq = 32;    // C/8
constexpr int Nn = 4096;  // tokens (64*64)
constexpr float LOG2E = 1.44269504088896340736f;

__device__ inline floatx16 zero16() {
  floatx16 z;
#pragma unroll
  for (int i = 0; i < 16; ++i) z[i] = 0.f;
  return z;
}

// ---------------------------------------------------------------------------
// Kernel 0: blocks [0,1024): x[b][c][n] fp32 -> xT[b][n][c] f16 (LDS transpose)
//           blocks [1024,1104): W fp32 -> f16 (Wf scaled by log2e)
// ---------------------------------------------------------------------------
__global__ __launch_bounds__(256) void k_xt(
    const float* __restrict__ x, _Float16* __restrict__ xT,
    const float* __restrict__ Wf, const float* __restrict__ Wg,
    const float* __restrict__ Wh, _Float16* __restrict__ Wfh,
    _Float16* __restrict__ Wgh, _Float16* __restrict__ Whh) {
  int blk = blockIdx.x;
  if (blk >= 1024) {
    int e = ((blk - 1024) * 256 + threadIdx.x) * 4;
    const float* src;
    _Float16* dst;
    float sc = 1.f;
    if (e < 8192) { src = Wf + e; dst = Wfh + e; sc = LOG2E; }
    else if (e < 16384) { src = Wg + (e - 8192); dst = Wgh + (e - 8192); }
    else { src = Wh + (e - 16384); dst = Whh + (e - 16384); }
    float4 v = *(const float4*)src;
    half4 o;
    o[0] = (_Float16)(v.x * sc); o[1] = (_Float16)(v.y * sc);
    o[2] = (_Float16)(v.z * sc); o[3] = (_Float16)(v.w * sc);
    *(half4*)dst = o;
    return;
  }
  __shared__ _Float16 t[64 * 66];
  int b = blk >> 8;
  int rem = blk & 255;
  int ct = rem & 3, nt = rem >> 2;
  int c0 = ct * 64, n0 = nt * 64;
  int tid = threadIdx.x;
  int col = tid & 63, row4 = tid >> 6;
  const float* xp = x + ((size_t)b * Cc + c0) * Nn + n0;
#pragma unroll
  for (int it = 0; it < 16; ++it) {
    int cl = it * 4 + row4;
    t[cl * 66 + col] = (_Float16)xp[(size_t)cl * Nn + col];
  }
  __syncthreads();
  _Float16* op = xT + ((size_t)b * Nn + n0) * Cc + c0;
#pragma unroll
  for (int it = 0; it < 16; ++it) {
    int nl = it * 4 + row4;
    op[(size_t)nl * Cc + col] = t[col * 66 + nl];
  }
}

// ---------------------------------------------------------------------------
// Kernel 1: projections from pre-converted f16 weights.
// Q is pre-scaled by log2e for exp2-domain softmax.
// ---------------------------------------------------------------------------
__global__ __launch_bounds__(256) void k_proj(
    const _Float16* __restrict__ xT,
    const _Float16* __restrict__ Wfh, const float* __restrict__ bf,
    const _Float16* __restrict__ Wgh, const float* __restrict__ bg,
    const _Float16* __restrict__ Whh, const float* __restrict__ bh,
    _Float16* __restrict__ Q, _Float16* __restrict__ K,
    _Float16* __restrict__ Vt) {
  int tid = threadIdx.x;
  int wave = tid >> 6, lane = tid & 63;
  int ml = lane & 31, h = lane >> 5;
  int jid = blockIdx.x * 4 + wave;
  floatx16 acc = zero16();

  if (jid < 1024) {
    const _Float16* W = (jid < 512) ? Wfh : Wgh;
    const float* bias = (jid < 512) ? bf : bg;
    _Float16* dst = (jid < 512) ? Q : K;
    float bscale = (jid < 512) ? LOG2E : 1.f;
    int j2 = jid & 511;
    int b = j2 >> 7, nt = j2 & 127;
    int n0 = nt * 32;
    const _Float16* ap = xT + ((size_t)b * Nn + n0 + ml) * Cc + h * 8;
    const _Float16* wp = W + (size_t)ml * Cc + h * 8;
#pragma unroll
    for (int kc = 0; kc < 16; ++kc) {
      half8 a = *(const half8*)(ap + kc * 16);
      half8 wv = *(const half8*)(wp + kc * 16);
      acc = MFMA_F16(a, wv, acc);
    }
    float bv = bias[ml] * bscale;
    _Float16* op = dst + ((size_t)b * Nn + n0) * Cq + ml;
#pragma unroll
    for (int r = 0; r < 16; ++r) {
      int row = (r & 3) + 8 * (r >> 2) + 4 * h;
      op[(size_t)row * Cq] = (_Float16)(acc[r] + bv);
    }
  } else {
    int v = jid - 1024;
    int b = v >> 10, r2 = v & 1023;
    int ct = r2 >> 7, nt = r2 & 127;
    int c0 = ct * 32, n0 = nt * 32;
    const _Float16* wp = Whh + (size_t)(c0 + ml) * Cc + h * 8;
    const _Float16* bp = xT + ((size_t)b * Nn + n0 + ml) * Cc + h * 8;
#pragma unroll
    for (int kc = 0; kc < 16; ++kc) {
      half8 wv = *(const half8*)(wp + kc * 16);
      half8 bfrag = *(const half8*)(bp + kc * 16);
      acc = MFMA_F16(wv, bfrag, acc);
    }
    _Float16* op = Vt + ((size_t)b * Cc + c0) * (size_t)Nn + n0 + ml;
#pragma unroll
    for (int q = 0; q < 4; ++q) {
      float4 bq = *(const float4*)(bh + c0 + 8 * q + 4 * h);
      const float* bqp = (const float*)&bq;
#pragma unroll
      for (int i = 0; i < 4; ++i) {
        int row = 8 * q + 4 * h + i;
        op[(size_t)row * Nn] = (_Float16)(acc[4 * q + i] + bqp[i]);
      }
    }
  }
}

// ---------------------------------------------------------------------------
// Kernel 2: pass-1 row max (log2-domain). MFMA bitwise identical to k_attn's
// S computation -> exp2(s - M) <= 1 exactly.
// ---------------------------------------------------------------------------
__global__ __launch_bounds__(512) void k_rowmax(const _Float16* __restrict__ Q,
                                                const _Float16* __restrict__ K,
                                                float* __restrict__ M) {
  __shared__ float red[8][32];
  int tid = threadIdx.x, w = tid >> 6, lane = tid & 63;
  int ml = lane & 31, h = lane >> 5;
  int b = blockIdx.x >> 7, mt = blockIdx.x & 127;
  int m0 = mt * 32;
  const _Float16* qp = Q + ((size_t)b * Nn + m0 + ml) * Cq + h * 8;
  half8 qb0 = *(const half8*)(qp);
  half8 qb1 = *(const half8*)(qp + 16);
  const _Float16* kp = K + ((size_t)b * Nn + w * 512 + ml) * Cq + h * 8;
  float mx = -3.0e38f;
  for (int t = 0; t < 16; ++t) {
    floatx16 s = zero16();
    half8 k0 = *(const half8*)(kp + (size_t)t * 32 * Cq);
    half8 k1 = *(const half8*)(kp + (size_t)t * 32 * Cq + 16);
    s = MFMA_F16(k0, qb0, s);
    s = MFMA_F16(k1, qb1, s);
#pragma unroll
    for (int i = 0; i < 16; ++i) mx = fmaxf(mx, s[i]);
  }
  mx = fmaxf(mx, __shfl_xor(mx, 32, 64));
  if (h == 0) red[w][ml] = mx;
  __syncthreads();
  if (tid < 32) {
    float m2 = red[0][tid];
#pragma unroll
    for (int i = 1; i < 8; ++i) m2 = fmaxf(m2, red[i][tid]);
    M[(size_t)b * Nn + m0 + tid] = m2;
  }
}

// ---------------------------------------------------------------------------
// Kernel 3: pass-2 attention v5 — 2x2 register tiling, 4 waves/block.
// Block = 256 thr (4 waves), covers 64 m x 256 c x nspan.
// S phase: wave w computes n-stripe nq=w (32 n) for BOTH m-halves (K frags
// reused), exp2 -> P[buf] (XOR-swizzled, ds_write_b64).
// PV phase: wave w covers c in [w*64,(w+1)*64): per kc, 2 V half8 (global)
// + 2 P b128 (LDS) + 4 MFMA -> halves LDS reads per MFMA vs v4.
// Single barrier/iter, double-buffered P (write(t+1) after barrier(t)).
// Grid: NC*256 blocks -> 4 blocks/CU at NC=4 (4 independent barrier groups).
// Outputs unnormalized f16 O-partials + fp32 l-partials; k_fin combines.
// ---------------------------------------------------------------------------
__global__ __launch_bounds__(256, 4) void k_attn(
    const _Float16* __restrict__ Q, const _Float16* __restrict__ K,
    const _Float16* __restrict__ Vt, const float* __restrict__ M,
    _Float16* __restrict__ Opart, float* __restrict__ lpart, int nspan) {
  __shared__ _Float16 P[2 * 64 * 128];
  __shared__ float lred[4][2][32];
  int tid = threadIdx.x, w = tid >> 6, lane = tid & 63;
  int ml = lane & 31, h = lane >> 5;
  int bx = blockIdx.x;
  int mt = bx & 63, b = (bx >> 6) & 3, nc = bx >> 8;
  int m0 = mt * 64;
  int nbase0 = nc * nspan;
  int sw = ml & 15;

  // Q fragments for both m-halves (cols m0+ml and m0+32+ml)
  const _Float16* qpb = Q + ((size_t)b * Nn + m0 + ml) * Cq + h * 8;
  half8 qb00 = *(const half8*)(qpb);
  half8 qb01 = *(const half8*)(qpb + 16);
  half8 qb10 = *(const half8*)(qpb + (size_t)32 * Cq);
  half8 qb11 = *(const half8*)(qpb + (size_t)32 * Cq + 16);
  float Mv0 = M[(size_t)b * Nn + m0 + ml];
  float Mv1 = M[(size_t)b * Nn + m0 + 32 + ml];
  float lacc0 = 0.f, lacc1 = 0.f;

  const _Float16* kbase =
      K + ((size_t)b * Nn + nbase0 + w * 32 + ml) * Cq + h * 8;
  int c0 = w * 64;
  const _Float16* vb0 =
      Vt + ((size_t)b * Cc + c0 + ml) * (size_t)Nn + nbase0 + h * 8;
  const _Float16* vb1 = vb0 + (size_t)32 * Nn;

  floatx16 o00 = zero16(), o01 = zero16(), o10 = zero16(), o11 = zero16();
  int iters = nspan >> 7;
  _Float16* pr0 = &P[ml * 128];         // m-half 0 rows
  _Float16* pr1 = &P[(32 + ml) * 128];  // m-half 1 rows

  for (int it = 0; it < iters; ++it) {
    int bufo = (it & 1) * (64 * 128);
    // ---- S phase: K fragments loaded once, used for both m-halves ----
    const _Float16* kp = kbase + (size_t)it * 128 * Cq;
    half8 k0 = *(const half8*)(kp);
    half8 k1 = *(const half8*)(kp + 16);
    {
      floatx16 s = zero16();
      s = MFMA_F16(k0, qb00, s);
      s = MFMA_F16(k1, qb01, s);
#pragma unroll
      for (int q = 0; q < 4; ++q) {
        float p0 = exp2f(s[4 * q + 0] - Mv0);
        float p1 = exp2f(s[4 * q + 1] - Mv0);
        float p2 = exp2f(s[4 * q + 2] - Mv0);
        float p3 = exp2f(s[4 * q + 3] - Mv0);
        lacc0 += (p0 + p1) + (p2 + p3);
        half4 pk;
        pk[0] = (_Float16)p0; pk[1] = (_Float16)p1;
        pk[2] = (_Float16)p2; pk[3] = (_Float16)p3;
        *(half4*)(pr0 + bufo + ((w * 4 + q) ^ sw) * 8 + 4 * h) = pk;
      }
    }
    {
      floatx16 s = zero16();
      s = MFMA_F16(k0, qb10, s);
      s = MFMA_F16(k1, qb11, s);
#pragma unroll
      for (int q = 0; q < 4; ++q) {
        float p0 = exp2f(s[4 * q + 0] - Mv1);
        float p1 = exp2f(s[4 * q + 1] - Mv1);
        float p2 = exp2f(s[4 * q + 2] - Mv1);
        float p3 = exp2f(s[4 * q + 3] - Mv1);
        lacc1 += (p0 + p1) + (p2 + p3);
        half4 pk;
        pk[0] = (_Float16)p0; pk[1] = (_Float16)p1;
        pk[2] = (_Float16)p2; pk[3] = (_Float16)p3;
        *(half4*)(pr1 + bufo + ((w * 4 + q) ^ sw) * 8 + 4 * h) = pk;
      }
    }
    __syncthreads();
    // ---- PV phase: 2x2 tile, 4 MFMA per (2 V-loads + 2 P-reads) ----
    const _Float16* vp0 = vb0 + it * 128;
    const _Float16* vp1 = vb1 + it * 128;
#pragma unroll
    for (int kc = 0; kc < 8; ++kc) {
      half8 vf0 = *(const half8*)(vp0 + kc * 16);
      half8 vf1 = *(const half8*)(vp1 + kc * 16);
      int chunk = (kc * 2 + h) ^ sw;
      half8 pb0 = *(const half8*)(pr0 + bufo + chunk * 8);  // ds_read_b128
      half8 pb1 = *(const half8*)(pr1 + bufo + chunk * 8);
      o00 = MFMA_F16(vf0, pb0, o00);
      o01 = MFMA_F16(vf0, pb1, o01);
      o10 = MFMA_F16(vf1, pb0, o10);
      o11 = MFMA_F16(vf1, pb1, o11);
    }
  }

  // ---- l reduction ----
  lacc0 += __shfl_xor(lacc0, 32, 64);
  lacc1 += __shfl_xor(lacc1, 32, 64);
  if (h == 0) {
    lred[w][0][ml] = lacc0;
    lred[w][1][ml] = lacc1;
  }
  __syncthreads();
  if (w == 0) {
    float ls = lred[0][h][ml] + lred[1][h][ml] + lred[2][h][ml] + lred[3][h][ml];
    lpart[((size_t)nc * Bn + b) * Nn + m0 + h * 32 + ml] = ls;
  }

  // ---- store unnormalized O^T partials (f16) ----
  _Float16* opb =
      Opart + ((size_t)nc * Bn + b) * Cc * (size_t)Nn + m0 + ml;
#pragma unroll
  for (int r = 0; r < 16; ++r) {
    int crow = (r & 3) + 8 * (r >> 2) + 4 * h;
    opb[(size_t)(c0 + crow) * Nn] = (_Float16)o00[r];
    opb[(size_t)(c0 + crow) * Nn + 32] = (_Float16)o01[r];
    opb[(size_t)(c0 + 32 + crow) * Nn] = (_Float16)o10[r];
    opb[(size_t)(c0 + 32 + crow) * Nn + 32] = (_Float16)o11[r];
  }
}

// ---------------------------------------------------------------------------
// Kernel 4: combine chunk partials: out = gamma*(sum O)/(sum l) + input
// ---------------------------------------------------------------------------
__global__ __launch_bounds__(256) void k_fin(const _Float16* __restrict__ Op,
                                             const float* __restrict__ lp,
                                             const float* __restrict__ inp,
                                             const float* __restrict__ gamma,
                                             float* __restrict__ out, int NC) {
  int i4 = (blockIdx.x * 256 + threadIdx.x) * 4;
  int m = i4 & (Nn - 1);
  int bc = i4 >> 12;        // b*256 + c
  int b = bc >> 8;
  float ax = 0.f, ay = 0.f, az = 0.f, aw = 0.f;
  float lx = 0.f, ly = 0.f, lz = 0.f, lw = 0.f;
  for (int nc = 0; nc < NC; ++nc) {
    half4 o = *(const half4*)(Op + ((size_t)nc * Bn * Cc + bc) * Nn + m);
    float4 lv = *(const float4*)(lp + ((size_t)nc * Bn + b) * Nn + m);
    ax += (float)o[0]; ay += (float)o[1]; az += (float)o[2]; aw += (float)o[3];
    lx += lv.x; ly += lv.y; lz += lv.z; lw += lv.w;
  }
  float g = gamma[0];
  float4 xi = *(const float4*)(inp + (size_t)i4);
  float4 r;
  r.x = g * ax / lx + xi.x;
  r.y = g * ay / ly + xi.y;
  r.z = g * az / lz + xi.z;
  r.w = g * aw / lw + xi.w;
  *(float4*)(out + (size_t)i4) = r;
}

// ---------------------------------------------------------------------------
extern "C" void kernel_launch(void* const* d_in, const int* in_sizes, int n_in,
                              void* d_out, int out_size, void* d_ws,
                              size_t ws_size, hipStream_t stream) {
  const float* x = (const float*)d_in[0];
  const float* Wf = (const float*)d_in[1];
  const float* bf = (const float*)d_in[2];
  const float* Wg = (const float*)d_in[3];
  const float* bg = (const float*)d_in[4];
  const float* Wh = (const float*)d_in[5];
  const float* bh = (const float*)d_in[6];
  const float* gamma = (const float*)d_in[7];
  float* out = (float*)d_out;

  char* ws = (char*)d_ws;
  // Layout (bytes):
  //   Q      [0,        1048576)
  //   K      [1048576,  2097152)
  //   Vt     [2097152, 10485760)
  //   M      [10485760, 10551296)
  //   Wfh    [10551296, 10567680)
  //   Wgh    [10567680, 10584064)
  //   Whh    [10584064, 10715136)
  //   lpart  [10715136, 10977280)   (up to 4 chunks x 64 KB)
  //   xT     [10977280, 19365888)   (dead after k_proj)
  //   Opart  [10977280, 10977280 + NC*8388608)  (overlays xT)
  _Float16* Q  = (_Float16*)(ws);
  _Float16* K  = (_Float16*)(ws + 1048576);
  _Float16* Vt = (_Float16*)(ws + 2097152);
  float*    M  = (float*)   (ws + 10485760);
  _Float16* Wfh = (_Float16*)(ws + 10551296);
  _Float16* Wgh = (_Float16*)(ws + 10567680);
  _Float16* Whh = (_Float16*)(ws + 10584064);
  float*    lpart = (float*)(ws + 10715136);
  _Float16* xT = (_Float16*)(ws + 10977280);
  _Float16* Opart = (_Float16*)(ws + 10977280);

  size_t base = 10977280u;
  int NC = 1;
  if (ws_size >= base + 4u * 8388608u) NC = 4;
  else if (ws_size >= base + 2u * 8388608u) NC = 2;
  int nspan = Nn / NC;

  k_xt<<<dim3(1104), dim3(256), 0, stream>>>(x, xT, Wf, Wg, Wh, Wfh, Wgh, Whh);
  k_proj<<<dim3(1280), dim3(256), 0, stream>>>(xT, Wfh, bf, Wgh, bg, Whh, bh, Q, K, Vt);
  k_rowmax<<<dim3(512), dim3(512), 0, stream>>>(Q, K, M);
  k_attn<<<dim3(NC * 256), dim3(256), 0, stream>>>(Q, K, Vt, M, Opart, lpart, nspan);
  k_fin<<<dim3(4096), dim3(256), 0, stream>>>(Opart, lpart, x, gamma, out, NC);
}

// Round 7
// 198.500 us; speedup vs baseline: 1.1976x; 1.1976x over previous
//
#include <hip/hip_runtime.h>

typedef _Float16 half8 __attribute__((ext_vector_type(8)));
typedef _Float16 half4 __attribute__((ext_vector_type(4)));
typedef float floatx16 __attribute__((ext_vector_type(16)));

#define MFMA_F16(A, B, C) __builtin_amdgcn_mfma_f32_32x32x16_f16(A, B, C, 0, 0, 0)

constexpr int Bn = 4;     // batch
constexpr int Cc = 256;   // channels
constexpr int Cq = 32;    // C/8
constexpr int Nn = 4096;  // tokens (64*64)
constexpr float LOG2E = 1.44269504088896340736f;

__device__ inline floatx16 zero16() {
  floatx16 z;
#pragma unroll
  for (int i = 0; i < 16; ++i) z[i] = 0.f;
  return z;
}

// ---------------------------------------------------------------------------
// Kernel 0: W fp32 -> f16 (Wf scaled by log2e for exp2-domain softmax).
// 80 blocks x 256 thr x 4 elems = 81920 elements.
// ---------------------------------------------------------------------------
__global__ __launch_bounds__(256) void k_wconv(
    const float* __restrict__ Wf, const float* __restrict__ Wg,
    const float* __restrict__ Wh, _Float16* __restrict__ Wfh,
    _Float16* __restrict__ Wgh, _Float16* __restrict__ Whh) {
  int e = (blockIdx.x * 256 + threadIdx.x) * 4;
  const float* src;
  _Float16* dst;
  float sc = 1.f;
  if (e < 8192) { src = Wf + e; dst = Wfh + e; sc = LOG2E; }
  else if (e < 16384) { src = Wg + (e - 8192); dst = Wgh + (e - 8192); }
  else { src = Wh + (e - 16384); dst = Whh + (e - 16384); }
  float4 v = *(const float4*)src;
  half4 o;
  o[0] = (_Float16)(v.x * sc); o[1] = (_Float16)(v.y * sc);
  o[2] = (_Float16)(v.z * sc); o[3] = (_Float16)(v.w * sc);
  *(half4*)dst = o;
}

// ---------------------------------------------------------------------------
// Kernel 1: projections straight from x[b][c][n] — NO transpose pass.
// The MFMA B-fragment of x is B[k=c][col=n]: lane ml -> n (n0+ml, coalesced),
// k = h*8+j -> 8 dword loads strided by Nn. Computes:
//   Q^T/K^T: D[o][n] = A(W[o][c]) * B(x[c][n])      (o=32 rows)
//   V^T:     D[c][n] = A(Wh[c][ci]) * B(x[ci][n])   (8 c-tiles)
// Block = (b, 32-token slice): 10 output tiles over 4 waves (w, w+4, w+8).
// x tile (32 KB) is re-read per tile but L1/L2-resident.
// ---------------------------------------------------------------------------
__global__ __launch_bounds__(256) void k_proj(
    const float* __restrict__ x,
    const _Float16* __restrict__ Wfh, const float* __restrict__ bf,
    const _Float16* __restrict__ Wgh, const float* __restrict__ bg,
    const _Float16* __restrict__ Whh, const float* __restrict__ bh,
    _Float16* __restrict__ Q, _Float16* __restrict__ K,
    _Float16* __restrict__ Vt) {
  int tid = threadIdx.x;
  int w = tid >> 6, lane = tid & 63;
  int ml = lane & 31, h = lane >> 5;
  int b = blockIdx.x >> 7, nt = blockIdx.x & 127;
  int n0 = nt * 32;
  const float* xb = x + (size_t)b * Cc * Nn + n0 + ml;

  for (int t = w; t < 10; t += 4) {
    const _Float16* W;
    const float* bias;
    float bscale = 1.f;
    int o0 = 0;
    if (t == 0) { W = Wfh; bias = bf; bscale = LOG2E; }
    else if (t == 1) { W = Wgh; bias = bg; }
    else { W = Whh + (size_t)(t - 2) * 32 * Cc; bias = bh + (t - 2) * 32; o0 = (t - 2) * 32; }

    floatx16 acc = zero16();
    const _Float16* wp = W + (size_t)ml * Cc + h * 8;
#pragma unroll
    for (int kc = 0; kc < 16; ++kc) {
      half8 a = *(const half8*)(wp + kc * 16);
      const float* xp = xb + (size_t)(kc * 16 + h * 8) * Nn;
      half8 bfr;
#pragma unroll
      for (int j = 0; j < 8; ++j) bfr[j] = (_Float16)xp[(size_t)j * Nn];
      acc = MFMA_F16(a, bfr, acc);
    }

    if (t < 2) {
      // Q^T/K^T -> store token-major Q[b][n][o]
      _Float16* dst = (t == 0) ? Q : K;
      _Float16* op = dst + ((size_t)b * Nn + n0 + ml) * Cq;
#pragma unroll
      for (int qd = 0; qd < 4; ++qd) {
        float4 bq = *(const float4*)(bias + 8 * qd + 4 * h);
        const float* bqp = (const float*)&bq;
#pragma unroll
        for (int i = 0; i < 4; ++i) {
          int crow = i + 8 * qd + 4 * h;
          op[crow] = (_Float16)(acc[4 * qd + i] + bqp[i] * bscale);
        }
      }
    } else {
      // V^T -> store channel-major Vt[b][c][n] (contiguous n = coalesced)
      _Float16* op = Vt + ((size_t)b * Cc + o0) * (size_t)Nn + n0 + ml;
#pragma unroll
      for (int qd = 0; qd < 4; ++qd) {
        float4 bq = *(const float4*)(bias + 8 * qd + 4 * h);
        const float* bqp = (const float*)&bq;
#pragma unroll
        for (int i = 0; i < 4; ++i) {
          int crow = i + 8 * qd + 4 * h;
          op[(size_t)crow * Nn] = (_Float16)(acc[4 * qd + i] + bqp[i]);
        }
      }
    }
  }
}

// ---------------------------------------------------------------------------
// Kernel 2: pass-1 row max (log2-domain). MFMA bitwise identical to k_attn's
// S computation -> exp2(s - M) <= 1 exactly.
// ---------------------------------------------------------------------------
__global__ __launch_bounds__(512) void k_rowmax(const _Float16* __restrict__ Q,
                                                const _Float16* __restrict__ K,
                                                float* __restrict__ M) {
  __shared__ float red[8][32];
  int tid = threadIdx.x, w = tid >> 6, lane = tid & 63;
  int ml = lane & 31, h = lane >> 5;
  int b = blockIdx.x >> 7, mt = blockIdx.x & 127;
  int m0 = mt * 32;
  const _Float16* qp = Q + ((size_t)b * Nn + m0 + ml) * Cq + h * 8;
  half8 qb0 = *(const half8*)(qp);
  half8 qb1 = *(const half8*)(qp + 16);
  const _Float16* kp = K + ((size_t)b * Nn + w * 512 + ml) * Cq + h * 8;
  float mx = -3.0e38f;
  for (int t = 0; t < 16; ++t) {
    floatx16 s = zero16();
    half8 k0 = *(const half8*)(kp + (size_t)t * 32 * Cq);
    half8 k1 = *(const half8*)(kp + (size_t)t * 32 * Cq + 16);
    s = MFMA_F16(k0, qb0, s);
    s = MFMA_F16(k1, qb1, s);
#pragma unroll
    for (int i = 0; i < 16; ++i) mx = fmaxf(mx, s[i]);
  }
  mx = fmaxf(mx, __shfl_xor(mx, 32, 64));
  if (h == 0) red[w][ml] = mx;
  __syncthreads();
  if (tid < 32) {
    float m2 = red[0][tid];
#pragma unroll
    for (int i = 1; i < 8; ++i) m2 = fmaxf(m2, red[i][tid]);
    M[(size_t)b * Nn + m0 + tid] = m2;
  }
}

// ---------------------------------------------------------------------------
// Kernel 3: pass-2 attention v6 — c-split for 4 barrier groups/CU at NC=2.
// Grid: NC(2) x b(4) x ch(2) x mt(64) = 1024 blocks of 256 thr (4 waves).
// LDS 33KB -> 4 blocks/CU = 16 waves/CU, 4 INDEPENDENT barrier groups.
// S phase (redundant per c-half, overlappable VALU): wave w computes
// n-stripe w (32 n) for both m-halves of the 64m x 128n P tile, exp2 -> LDS
// (XOR 16B-chunk swizzle: chunk' = chunk ^ (ml&15); write b64, read b128
// conflict-free). PV: wave w covers c = ch*128 + w*32, both m-halves:
// per kc 1 V half8 + 2 P b128 + 2 MFMA. Single barrier/iter, double-buffered.
// Outputs unnormalized f16 O-partials + fp32 l-partials; k_fin combines.
// (Both ch blocks write identical lpart values — benign deterministic dup.)
// ---------------------------------------------------------------------------
__global__ __launch_bounds__(256, 4) void k_attn(
    const _Float16* __restrict__ Q, const _Float16* __restrict__ K,
    const _Float16* __restrict__ Vt, const float* __restrict__ M,
    _Float16* __restrict__ Opart, float* __restrict__ lpart, int nspan) {
  __shared__ _Float16 P[2 * 64 * 128];
  __shared__ float lred[4][2][32];
  int tid = threadIdx.x, w = tid >> 6, lane = tid & 63;
  int ml = lane & 31, h = lane >> 5;
  int bx = blockIdx.x;
  int mt = bx & 63, ch = (bx >> 6) & 1, b = (bx >> 7) & 3, nc = bx >> 9;
  int m0 = mt * 64;
  int nbase0 = nc * nspan;
  int sw = ml & 15;

  // Q fragments for both m-halves (cols m0+ml and m0+32+ml)
  const _Float16* qpb = Q + ((size_t)b * Nn + m0 + ml) * Cq + h * 8;
  half8 qb00 = *(const half8*)(qpb);
  half8 qb01 = *(const half8*)(qpb + 16);
  half8 qb10 = *(const half8*)(qpb + (size_t)32 * Cq);
  half8 qb11 = *(const half8*)(qpb + (size_t)32 * Cq + 16);
  float Mv0 = M[(size_t)b * Nn + m0 + ml];
  float Mv1 = M[(size_t)b * Nn + m0 + 32 + ml];
  float lacc0 = 0.f, lacc1 = 0.f;

  const _Float16* kbase =
      K + ((size_t)b * Nn + nbase0 + w * 32 + ml) * Cq + h * 8;
  int c0 = ch * 128 + w * 32;
  const _Float16* vb0 =
      Vt + ((size_t)b * Cc + c0 + ml) * (size_t)Nn + nbase0 + h * 8;

  floatx16 o0 = zero16(), o1 = zero16();
  int iters = nspan >> 7;
  _Float16* pr0 = &P[ml * 128];         // m-half 0 rows
  _Float16* pr1 = &P[(32 + ml) * 128];  // m-half 1 rows

  for (int it = 0; it < iters; ++it) {
    int bufo = (it & 1) * (64 * 128);
    // ---- S phase: K fragments loaded once, used for both m-halves ----
    const _Float16* kp = kbase + (size_t)it * 128 * Cq;
    half8 k0 = *(const half8*)(kp);
    half8 k1 = *(const half8*)(kp + 16);
    {
      floatx16 s = zero16();
      s = MFMA_F16(k0, qb00, s);
      s = MFMA_F16(k1, qb01, s);
#pragma unroll
      for (int q = 0; q < 4; ++q) {
        float p0 = exp2f(s[4 * q + 0] - Mv0);
        float p1 = exp2f(s[4 * q + 1] - Mv0);
        float p2 = exp2f(s[4 * q + 2] - Mv0);
        float p3 = exp2f(s[4 * q + 3] - Mv0);
        lacc0 += (p0 + p1) + (p2 + p3);
        half4 pk;
        pk[0] = (_Float16)p0; pk[1] = (_Float16)p1;
        pk[2] = (_Float16)p2; pk[3] = (_Float16)p3;
        *(half4*)(pr0 + bufo + (((w * 4 + q) ^ sw)) * 8 + 4 * h) = pk;
      }
    }
    {
      floatx16 s = zero16();
      s = MFMA_F16(k0, qb10, s);
      s = MFMA_F16(k1, qb11, s);
#pragma unroll
      for (int q = 0; q < 4; ++q) {
        float p0 = exp2f(s[4 * q + 0] - Mv1);
        float p1 = exp2f(s[4 * q + 1] - Mv1);
        float p2 = exp2f(s[4 * q + 2] - Mv1);
        float p3 = exp2f(s[4 * q + 3] - Mv1);
        lacc1 += (p0 + p1) + (p2 + p3);
        half4 pk;
        pk[0] = (_Float16)p0; pk[1] = (_Float16)p1;
        pk[2] = (_Float16)p2; pk[3] = (_Float16)p3;
        *(half4*)(pr1 + bufo + (((w * 4 + q) ^ sw)) * 8 + 4 * h) = pk;
      }
    }
    __syncthreads();
    // ---- PV phase: wave = 32 c x 64 m: 1 V load + 2 P reads + 2 MFMA ----
    const _Float16* vp0 = vb0 + it * 128;
#pragma unroll
    for (int kc = 0; kc < 8; ++kc) {
      half8 vf0 = *(const half8*)(vp0 + kc * 16);
      int chunk = (kc * 2 + h) ^ sw;
      half8 pb0 = *(const half8*)(pr0 + bufo + chunk * 8);  // ds_read_b128
      half8 pb1 = *(const half8*)(pr1 + bufo + chunk * 8);
      o0 = MFMA_F16(vf0, pb0, o0);
      o1 = MFMA_F16(vf0, pb1, o1);
    }
  }

  // ---- l reduction (identical values computed by both ch blocks) ----
  lacc0 += __shfl_xor(lacc0, 32, 64);
  lacc1 += __shfl_xor(lacc1, 32, 64);
  if (h == 0) {
    lred[w][0][ml] = lacc0;
    lred[w][1][ml] = lacc1;
  }
  __syncthreads();
  if (w == 0) {
    float ls = lred[0][h][ml] + lred[1][h][ml] + lred[2][h][ml] + lred[3][h][ml];
    lpart[((size_t)nc * Bn + b) * Nn + m0 + h * 32 + ml] = ls;
  }

  // ---- store unnormalized O^T partials (f16) ----
  _Float16* opb =
      Opart + ((size_t)nc * Bn + b) * Cc * (size_t)Nn + m0 + ml;
#pragma unroll
  for (int r = 0; r < 16; ++r) {
    int crow = (r & 3) + 8 * (r >> 2) + 4 * h;
    opb[(size_t)(c0 + crow) * Nn] = (_Float16)o0[r];
    opb[(size_t)(c0 + crow) * Nn + 32] = (_Float16)o1[r];
  }
}

// ---------------------------------------------------------------------------
// Kernel 4: combine chunk partials: out = gamma*(sum O)/(sum l) + input
// ---------------------------------------------------------------------------
__global__ __launch_bounds__(256) void k_fin(const _Float16* __restrict__ Op,
                                             const float* __restrict__ lp,
                                             const float* __restrict__ inp,
                                             const float* __restrict__ gamma,
                                             float* __restrict__ out, int NC) {
  int i4 = (blockIdx.x * 256 + threadIdx.x) * 4;
  int m = i4 & (Nn - 1);
  int bc = i4 >> 12;        // b*256 + c
  int b = bc >> 8;
  float ax = 0.f, ay = 0.f, az = 0.f, aw = 0.f;
  float lx = 0.f, ly = 0.f, lz = 0.f, lw = 0.f;
  for (int nc = 0; nc < NC; ++nc) {
    half4 o = *(const half4*)(Op + ((size_t)nc * Bn * Cc + bc) * Nn + m);
    float4 lv = *(const float4*)(lp + ((size_t)nc * Bn + b) * Nn + m);
    ax += (float)o[0]; ay += (float)o[1]; az += (float)o[2]; aw += (float)o[3];
    lx += lv.x; ly += lv.y; lz += lv.z; lw += lv.w;
  }
  float g = gamma[0];
  float4 xi = *(const float4*)(inp + (size_t)i4);
  float4 r;
  r.x = g * ax / lx + xi.x;
  r.y = g * ay / ly + xi.y;
  r.z = g * az / lz + xi.z;
  r.w = g * aw / lw + xi.w;
  *(float4*)(out + (size_t)i4) = r;
}

// ---------------------------------------------------------------------------
extern "C" void kernel_launch(void* const* d_in, const int* in_sizes, int n_in,
                              void* d_out, int out_size, void* d_ws,
                              size_t ws_size, hipStream_t stream) {
  const float* x = (const float*)d_in[0];
  const float* Wf = (const float*)d_in[1];
  const float* bf = (const float*)d_in[2];
  const float* Wg = (const float*)d_in[3];
  const float* bg = (const float*)d_in[4];
  const float* Wh = (const float*)d_in[5];
  const float* bh = (const float*)d_in[6];
  const float* gamma = (const float*)d_in[7];
  float* out = (float*)d_out;

  char* ws = (char*)d_ws;
  // Layout (bytes):
  //   Q      [0,        1048576)
  //   K      [1048576,  2097152)
  //   Vt     [2097152, 10485760)
  //   M      [10485760, 10551296)
  //   Wfh    [10551296, 10567680)
  //   Wgh    [10567680, 10584064)
  //   Whh    [10584064, 10715136)
  //   lpart  [10715136, 10846208)   (2 chunks x 64 KB)
  //   Opart  [10846208, 10846208 + NC*8388608)
  _Float16* Q  = (_Float16*)(ws);
  _Float16* K  = (_Float16*)(ws + 1048576);
  _Float16* Vt = (_Float16*)(ws + 2097152);
  float*    M  = (float*)   (ws + 10485760);
  _Float16* Wfh = (_Float16*)(ws + 10551296);
  _Float16* Wgh = (_Float16*)(ws + 10567680);
  _Float16* Whh = (_Float16*)(ws + 10584064);
  float*    lpart = (float*)(ws + 10715136);
  _Float16* Opart = (_Float16*)(ws + 10846208);

  size_t base = 10846208u;
  int NC = (ws_size >= base + 2u * 8388608u) ? 2 : 1;
  int nspan = Nn / NC;

  k_wconv<<<dim3(80), dim3(256), 0, stream>>>(Wf, Wg, Wh, Wfh, Wgh, Whh);
  k_proj<<<dim3(512), dim3(256), 0, stream>>>(x, Wfh, bf, Wgh, bg, Whh, bh, Q, K, Vt);
  k_rowmax<<<dim3(512), dim3(512), 0, stream>>>(Q, K, M);
  k_attn<<<dim3(NC * 512), dim3(256), 0, stream>>>(Q, K, Vt, M, Opart, lpart, nspan);
  k_fin<<<dim3(4096), dim3(256), 0, stream>>>(Opart, lpart, x, gamma, out, NC);
}